// Round 6
// baseline (1410.001 us; speedup 1.0000x reference)
//
#include <hip/hip_runtime.h>
#include <hip/hip_fp16.h>

#define TSTEPS 276
#define NBATCH 32768
#define KDIM   4416   // 276*16
#define NPAD   320    // Wfc rows padded to 2*160
#define NOUT   276
#define GBM    64     // gemm block M
#define NCHUNK 138    // KDIM / 32
#define ROWBLK_ELE (138 * 2048)  // elements per 64-row block of H (138 k-tiles)
#define BTILE_ELE  (320 * 32)    // elements per k-tile of W2t (10240)

typedef _Float16 half8 __attribute__((ext_vector_type(8)));
typedef float    f32x4 __attribute__((ext_vector_type(4)));

__device__ __forceinline__ float fast_sigmoid(float x) {
    float e = __builtin_amdgcn_exp2f(-1.4426950408889634f * x);
    return __builtin_amdgcn_rcpf(1.0f + e);
}
__device__ __forceinline__ float fast_tanh(float x) {
    float e = __builtin_amdgcn_exp2f(2.885390081777927f * x);
    return 1.0f - 2.0f * __builtin_amdgcn_rcpf(1.0f + e);
}

// broadcast h from lane (lane&0x18)|j within each 8-lane group (BitMode swizzle)
#define HSWZ(dst, hb, j) dst = __int_as_float(__builtin_amdgcn_ds_swizzle(hb, ((j) << 5) | 0x18))

// ---------------- Kernel 1: bidirectional LSTM (reverted to R4 = known good) --
// Issue-bound (VALUBusy ~100%). H written in gemm-native fragment tiles
// Ht[b/64][k/32][64][32] fp16: element (row bl, p=s*16+dir*8+j) ->
// (bl>>6)*ROWBLK + (p>>5)*2048 + (bl&63)*32 + (p&31).
__global__ __launch_bounds__(256, 4) void lstm_kernel(
    const float* __restrict__ x,
    const float* __restrict__ Wih_f, const float* __restrict__ Whh_f,
    const float* __restrict__ bih_f, const float* __restrict__ bhh_f,
    const float* __restrict__ Wih_b, const float* __restrict__ Whh_b,
    const float* __restrict__ bih_b, const float* __restrict__ bhh_b,
    int row0, _Float16* __restrict__ Hout)
{
    const int tid = threadIdx.x;
    const int k   = tid & 7;
    const int rd  = blockIdx.x * 32 + (tid >> 3);
    const int bl  = rd >> 1;
    const int dir = rd & 1;
    const int bg  = row0 + bl;

    const float* Wih = dir ? Wih_b : Wih_f;
    const float* Whh = dir ? Whh_b : Whh_f;
    const float* bih = dir ? bih_b : bih_f;
    const float* bhh = dir ? bhh_b : bhh_f;

    float Wk[4][8], Wi0[4], Wi1[4], bs[4];
    #pragma unroll
    for (int g = 0; g < 4; ++g) {
        int row = g * 8 + k;                       // PyTorch gate order i,f,g,o
        #pragma unroll
        for (int j = 0; j < 8; ++j) Wk[g][j] = Whh[row * 8 + j];
        Wi0[g] = Wih[row * 2 + 0];
        Wi1[g] = Wih[row * 2 + 1];
        bs[g]  = bih[row] + bhh[row];
    }
    // pin every weight in an ArchVGPR: forbids rematerialization/reload
    #pragma unroll
    for (int g = 0; g < 4; ++g) {
        #pragma unroll
        for (int j = 0; j < 8; ++j) asm volatile("" : "+v"(Wk[g][j]));
        asm volatile("" : "+v"(Wi0[g]));
        asm volatile("" : "+v"(Wi1[g]));
        asm volatile("" : "+v"(bs[g]));
    }

    const float2* __restrict__ xrow = (const float2*)(x + (size_t)bg * (TSTEPS * 2));
    // tiled store base: step s writes hp[(s&1)*16], advancing one k-tile
    // (2048 ele) after each odd s.
    _Float16* __restrict__ hp = Hout + (size_t)(bl >> 6) * ROWBLK_ELE
                                      + (bl & 63) * 32 + dir * 8 + k;

    float h = 0.0f, c = 0.0f;
    float2 xv = xrow[dir ? (TSTEPS - 1) : 0];
    #pragma unroll 2
    for (int s = 0; s < TSTEPS; ++s) {
        const int sn = (s + 1 < TSTEPS) ? (s + 1) : s;
        const float2 xv_n = xrow[dir ? (TSTEPS - 1 - sn) : sn];   // prefetch

        const int hb = __float_as_int(h);
        float hv[8];
        HSWZ(hv[0], hb, 0); HSWZ(hv[1], hb, 1); HSWZ(hv[2], hb, 2); HSWZ(hv[3], hb, 3);
        HSWZ(hv[4], hb, 4); HSWZ(hv[5], hb, 5); HSWZ(hv[6], hb, 6); HSWZ(hv[7], hb, 7);

        float a[4];
        #pragma unroll
        for (int g = 0; g < 4; ++g) {
            float acc = fmaf(xv.x, Wi0[g], bs[g]);
            acc = fmaf(xv.y, Wi1[g], acc);
            #pragma unroll
            for (int j = 0; j < 8; ++j) acc = fmaf(Wk[g][j], hv[j], acc);
            a[g] = acc;
        }
        const float ig = fast_sigmoid(a[0]);
        const float fg = fast_sigmoid(a[1]);
        const float gg = fast_tanh(a[2]);
        const float og = fast_sigmoid(a[3]);
        c = fmaf(fg, c, ig * gg);
        h = og * fast_tanh(c);

        hp[(s & 1) << 4] = (_Float16)h;            // kc = (s&1)*16 + dir*8 + j
        hp += (size_t)((s & 1) << 11);             // +2048 ele after odd steps
        xv = xv_n;
    }
}

// ---------------- Kernel 2: Wfc fp32 -> fp16, K-permutation + B-TILING ------
// (unchanged) W2t[k/32][320][32] fp16 = fragment-native B tiles.
__global__ __launch_bounds__(256) void conv_kernel(const float* __restrict__ Wfc,
                                                   _Float16* __restrict__ W2t)
{
    int i = blockIdx.x * 256 + threadIdx.x;        // destination index
    if (i < NPAD * KDIM) {
        int nk = i / BTILE_ELE;                    // k-tile index
        int r  = i - nk * BTILE_ELE;
        int n  = r >> 5;                           // 0..319 output row
        int kc = r & 31;
        int p  = nk * 32 + kc;                     // logical k
        _Float16 v = (_Float16)0.0f;
        if (n < NOUT) {
            int s = p >> 4, rr = p & 15;
            int src = (rr < 8) ? p : ((TSTEPS - 1 - s) * 16 + rr);
            v = (_Float16)Wfc[n * KDIM + src];
        }
        W2t[i] = v;
    }
}

// ---------------- Kernel 3: out[rows,276] = H[rows,4416] * W2t^T + bfc ------
// R6 REWRITE: direct fragment loads, ZERO LDS / barriers / ds_reads.
// The tiled layouts are MFMA-fragment-native: for mfma_f32_16x16x32_f16,
// lane(l15,l4) needs operand row l15, k-chunk l4 -> address
// tile + row*64 + l4*16 = a perfectly coalesced 1KB load per instruction,
// straight to VGPRs. Waves are fully independent (latency hidden by 1-chunk
// prefetch x 8 waves/CU); B (20KB/chunk, 2.76MB total) is L1/L2-resident,
// A streams from HBM exactly once. Evidence basis: R5 showed the LDS
// pipeline is serialization-bound (halving B volume REGRESSED when
// blocks/CU dropped 2->1); all byte floors are <=100us.
__global__ __launch_bounds__(256, 2) void gemm_kernel(
    const _Float16* __restrict__ H, const _Float16* __restrict__ W2,
    const float* __restrict__ bfc, float* __restrict__ out)
{
    const int tid  = threadIdx.x;
    const int lane = tid & 63;
    const int w    = tid >> 6;                     // 0..3
    const int wm   = w >> 1;                       // 32-row half of the 64-row tile
    const int wn   = w & 1;                        // 160-col half of N
    const int m0   = blockIdx.x * GBM;
    const int l15  = lane & 15;
    const int l4   = lane >> 4;

    // A fragment pointers (two 16-row sub-tiles), chunk stride 4096B = 256 half8
    const char* Atile = (const char*)(H + (size_t)(m0 >> 6) * ROWBLK_ELE);
    const half8* pa0 = (const half8*)(Atile + (wm * 32 +  0 + l15) * 64 + l4 * 16);
    const half8* pa1 = (const half8*)(Atile + (wm * 32 + 16 + l15) * 64 + l4 * 16);
    // B fragment pointers (ten 16-col sub-tiles), chunk stride 20480B = 1280 half8
    const half8* pb[10];
    #pragma unroll
    for (int ni = 0; ni < 10; ++ni)
        pb[ni] = (const half8*)((const char*)W2 + (wn * 160 + ni * 16 + l15) * 64 + l4 * 16);

    f32x4 acc[2][10] = {};

    half8 a0 = pa0[0], a1 = pa1[0];
    half8 b[10];
    #pragma unroll
    for (int ni = 0; ni < 10; ++ni) b[ni] = pb[ni][0];

    #pragma unroll 2
    for (int ck = 0; ck < NCHUNK - 1; ++ck) {
        const size_t oA = (size_t)(ck + 1) * 256;
        const size_t oB = (size_t)(ck + 1) * 1280;
        // prefetch chunk ck+1 while computing ck
        half8 na0 = pa0[oA], na1 = pa1[oA];
        half8 nb[10];
        #pragma unroll
        for (int ni = 0; ni < 10; ++ni) nb[ni] = pb[ni][oB];

        #pragma unroll
        for (int ni = 0; ni < 10; ++ni) {
            acc[0][ni] = __builtin_amdgcn_mfma_f32_16x16x32_f16(a0, b[ni], acc[0][ni], 0, 0, 0);
            acc[1][ni] = __builtin_amdgcn_mfma_f32_16x16x32_f16(a1, b[ni], acc[1][ni], 0, 0, 0);
        }
        a0 = na0; a1 = na1;
        #pragma unroll
        for (int ni = 0; ni < 10; ++ni) b[ni] = nb[ni];
    }
    // last chunk
    #pragma unroll
    for (int ni = 0; ni < 10; ++ni) {
        acc[0][ni] = __builtin_amdgcn_mfma_f32_16x16x32_f16(a0, b[ni], acc[0][ni], 0, 0, 0);
        acc[1][ni] = __builtin_amdgcn_mfma_f32_16x16x32_f16(a1, b[ni], acc[1][ni], 0, 0, 0);
    }

    // C layout (16x16): col = lane&15, row = (lane>>4)*4 + reg
    #pragma unroll
    for (int ni = 0; ni < 10; ++ni) {
        const int n = wn * 160 + ni * 16 + l15;
        if (n < NOUT) {
            const float bv = bfc[n];
            #pragma unroll
            for (int mi = 0; mi < 2; ++mi) {
                const int mbase = m0 + wm * 32 + mi * 16 + l4 * 4;
                #pragma unroll
                for (int g = 0; g < 4; ++g)
                    out[(size_t)(mbase + g) * NOUT + n] = acc[mi][ni][g] + bv;
            }
        }
    }
}

extern "C" void kernel_launch(void* const* d_in, const int* in_sizes, int n_in,
                              void* d_out, int out_size, void* d_ws, size_t ws_size,
                              hipStream_t stream) {
    const float* x     = (const float*)d_in[0];
    const float* Wih_f = (const float*)d_in[1];
    const float* Whh_f = (const float*)d_in[2];
    const float* bih_f = (const float*)d_in[3];
    const float* bhh_f = (const float*)d_in[4];
    const float* Wih_b = (const float*)d_in[5];
    const float* Whh_b = (const float*)d_in[6];
    const float* bih_b = (const float*)d_in[7];
    const float* bhh_b = (const float*)d_in[8];
    const float* Wfc   = (const float*)d_in[9];
    const float* bfc   = (const float*)d_in[10];
    float* out = (float*)d_out;

    // Workspace layout: [W2t: NPAD*KDIM fp16][H chunk (tiled): chunk*KDIM fp16]
    _Float16* W2 = (_Float16*)d_ws;
    size_t h_off = ((size_t)NPAD * KDIM * 2 + 255) & ~(size_t)255;
    size_t avail = (ws_size > h_off) ? (ws_size - h_off) : 0;
    long maxrows = (long)(avail / ((size_t)KDIM * 2));
    int chunk = (int)((maxrows / 128) * 128);
    if (chunk > NBATCH) chunk = NBATCH;
    if (chunk < 128)    chunk = 128;
    _Float16* Hc = (_Float16*)((char*)d_ws + h_off);

    conv_kernel<<<(NPAD * KDIM + 255) / 256, 256, 0, stream>>>(Wfc, W2);

    for (int r0 = 0; r0 < NBATCH; r0 += chunk) {
        int rows = NBATCH - r0; if (rows > chunk) rows = chunk;
        lstm_kernel<<<rows / 16, 256, 0, stream>>>(x, Wih_f, Whh_f, bih_f, bhh_f,
                                                   Wih_b, Whh_b, bih_b, bhh_b,
                                                   r0, Hc);
        gemm_kernel<<<rows / 64, 256, 0, stream>>>(Hc, W2, bfc,
                                                   out + (size_t)r0 * NOUT);
    }
}

// Round 7
// 834.803 us; speedup vs baseline: 1.6890x; 1.6890x over previous
//
#include <hip/hip_runtime.h>
#include <hip/hip_fp16.h>

#define TSTEPS 276
#define NBATCH 32768
#define KDIM   4416   // 276*16
#define NPAD   320    // Wfc rows padded to 2*160
#define NOUT   276
#define GBM    64     // gemm block M
#define NCHUNK 138    // KDIM / 32
#define ROWBLK_ELE (138 * 2048)  // elements per 64-row block of H (138 k-tiles)
#define BTILE_ELE  (320 * 32)    // elements per k-tile of W2t (10240)

typedef _Float16 half8 __attribute__((ext_vector_type(8)));
typedef float    f32x4 __attribute__((ext_vector_type(4)));

__device__ __forceinline__ float fast_sigmoid(float x) {
    float e = __builtin_amdgcn_exp2f(-1.4426950408889634f * x);
    return __builtin_amdgcn_rcpf(1.0f + e);
}
__device__ __forceinline__ float fast_tanh(float x) {
    float e = __builtin_amdgcn_exp2f(2.885390081777927f * x);
    return 1.0f - 2.0f * __builtin_amdgcn_rcpf(1.0f + e);
}

// broadcast h from lane (lane&0x18)|j within each 8-lane group (BitMode swizzle)
#define HSWZ(dst, hb, j) dst = __int_as_float(__builtin_amdgcn_ds_swizzle(hb, ((j) << 5) | 0x18))

// ---------------- Kernel 1: bidirectional LSTM (unchanged, known good) ------
// Issue-bound (VALUBusy ~100%). H written in gemm-native fragment tiles
// Ht[b/64][k/32][64][32] fp16.
__global__ __launch_bounds__(256, 4) void lstm_kernel(
    const float* __restrict__ x,
    const float* __restrict__ Wih_f, const float* __restrict__ Whh_f,
    const float* __restrict__ bih_f, const float* __restrict__ bhh_f,
    const float* __restrict__ Wih_b, const float* __restrict__ Whh_b,
    const float* __restrict__ bih_b, const float* __restrict__ bhh_b,
    int row0, _Float16* __restrict__ Hout)
{
    const int tid = threadIdx.x;
    const int k   = tid & 7;
    const int rd  = blockIdx.x * 32 + (tid >> 3);
    const int bl  = rd >> 1;
    const int dir = rd & 1;
    const int bg  = row0 + bl;

    const float* Wih = dir ? Wih_b : Wih_f;
    const float* Whh = dir ? Whh_b : Whh_f;
    const float* bih = dir ? bih_b : bih_f;
    const float* bhh = dir ? bhh_b : bhh_f;

    float Wk[4][8], Wi0[4], Wi1[4], bs[4];
    #pragma unroll
    for (int g = 0; g < 4; ++g) {
        int row = g * 8 + k;                       // PyTorch gate order i,f,g,o
        #pragma unroll
        for (int j = 0; j < 8; ++j) Wk[g][j] = Whh[row * 8 + j];
        Wi0[g] = Wih[row * 2 + 0];
        Wi1[g] = Wih[row * 2 + 1];
        bs[g]  = bih[row] + bhh[row];
    }
    // pin every weight in an ArchVGPR: forbids rematerialization/reload
    #pragma unroll
    for (int g = 0; g < 4; ++g) {
        #pragma unroll
        for (int j = 0; j < 8; ++j) asm volatile("" : "+v"(Wk[g][j]));
        asm volatile("" : "+v"(Wi0[g]));
        asm volatile("" : "+v"(Wi1[g]));
        asm volatile("" : "+v"(bs[g]));
    }

    const float2* __restrict__ xrow = (const float2*)(x + (size_t)bg * (TSTEPS * 2));
    _Float16* __restrict__ hp = Hout + (size_t)(bl >> 6) * ROWBLK_ELE
                                      + (bl & 63) * 32 + dir * 8 + k;

    float h = 0.0f, c = 0.0f;
    float2 xv = xrow[dir ? (TSTEPS - 1) : 0];
    #pragma unroll 2
    for (int s = 0; s < TSTEPS; ++s) {
        const int sn = (s + 1 < TSTEPS) ? (s + 1) : s;
        const float2 xv_n = xrow[dir ? (TSTEPS - 1 - sn) : sn];   // prefetch

        const int hb = __float_as_int(h);
        float hv[8];
        HSWZ(hv[0], hb, 0); HSWZ(hv[1], hb, 1); HSWZ(hv[2], hb, 2); HSWZ(hv[3], hb, 3);
        HSWZ(hv[4], hb, 4); HSWZ(hv[5], hb, 5); HSWZ(hv[6], hb, 6); HSWZ(hv[7], hb, 7);

        float a[4];
        #pragma unroll
        for (int g = 0; g < 4; ++g) {
            float acc = fmaf(xv.x, Wi0[g], bs[g]);
            acc = fmaf(xv.y, Wi1[g], acc);
            #pragma unroll
            for (int j = 0; j < 8; ++j) acc = fmaf(Wk[g][j], hv[j], acc);
            a[g] = acc;
        }
        const float ig = fast_sigmoid(a[0]);
        const float fg = fast_sigmoid(a[1]);
        const float gg = fast_tanh(a[2]);
        const float og = fast_sigmoid(a[3]);
        c = fmaf(fg, c, ig * gg);
        h = og * fast_tanh(c);

        hp[(s & 1) << 4] = (_Float16)h;            // kc = (s&1)*16 + dir*8 + j
        hp += (size_t)((s & 1) << 11);             // +2048 ele after odd steps
        xv = xv_n;
    }
}

// ---------------- Kernel 2: Wfc fp32 -> fp16, K-permutation + B-TILING ------
// (unchanged) W2t[k/32][320][32] fp16 = fragment-native B tiles.
__global__ __launch_bounds__(256) void conv_kernel(const float* __restrict__ Wfc,
                                                   _Float16* __restrict__ W2t)
{
    int i = blockIdx.x * 256 + threadIdx.x;        // destination index
    if (i < NPAD * KDIM) {
        int nk = i / BTILE_ELE;                    // k-tile index
        int r  = i - nk * BTILE_ELE;
        int n  = r >> 5;                           // 0..319 output row
        int kc = r & 31;
        int p  = nk * 32 + kc;                     // logical k
        _Float16 v = (_Float16)0.0f;
        if (n < NOUT) {
            int s = p >> 4, rr = p & 15;
            int src = (rr < 8) ? p : ((TSTEPS - 1 - s) * 16 + rr);
            v = (_Float16)Wfc[n * KDIM + src];
        }
        W2t[i] = v;
    }
}

// ---------------- Kernel 3: out[rows,276] = H[rows,4416] * W2t^T + bfc ------
// R7: direct fragment loads (no LDS/barriers, R6 structure) with the
// concurrency fixed. R6 counters: MfmaUtil 6.4 / VALU 2.3 / HBM 4.3% /
// Occ 24% -> pure latency-bound at 2 waves/SIMD with 12 loads per 10-MFMA
// window. Fix: 512-thread blocks (8 waves), wave tile 32x80:
//   - 7 loads (2 A + 5 B) per 10 MFMAs per chunk (was 12/20 at 32x160);
//   - acc 40 + frags 2x28 + addrs ~= 118 VGPR; __launch_bounds__(512,4)
//     caps at the 128-VGPR occupancy cliff -> 2 blocks/CU x 8 waves
//     = 16 waves/CU = 4 waves/SIMD (2x the latency streams of R6);
//   - B frags shared by 4 waves/CU (2 per wn per block x 2 blocks) via L1;
//     B L2 volume stays 1.4GB (512 blocks x 2.76MB).
__global__ __launch_bounds__(512, 4) void gemm_kernel(
    const _Float16* __restrict__ H, const _Float16* __restrict__ W2,
    const float* __restrict__ bfc, float* __restrict__ out)
{
    const int tid  = threadIdx.x;
    const int lane = tid & 63;
    const int w    = tid >> 6;                     // 0..7
    const int wm   = w & 1;                        // 32-row half of the 64-row tile
    const int wn   = w >> 1;                       // 80-col quarter of N=320
    const int m0   = blockIdx.x * GBM;
    const int l15  = lane & 15;
    const int l4   = lane >> 4;

    // A fragment pointers (two 16-row sub-tiles), chunk stride 4096B = 256 half8
    const char* Atile = (const char*)(H + (size_t)(m0 >> 6) * ROWBLK_ELE);
    const half8* pa0 = (const half8*)(Atile + (wm * 32 +  0 + l15) * 64 + l4 * 16);
    const half8* pa1 = (const half8*)(Atile + (wm * 32 + 16 + l15) * 64 + l4 * 16);
    // B fragment pointers (five 16-col sub-tiles), chunk stride 20480B = 1280 half8
    const half8* pb[5];
    #pragma unroll
    for (int ni = 0; ni < 5; ++ni)
        pb[ni] = (const half8*)((const char*)W2 + (wn * 80 + ni * 16 + l15) * 64 + l4 * 16);

    f32x4 acc[2][5] = {};

    half8 a0 = pa0[0], a1 = pa1[0];
    half8 b[5];
    #pragma unroll
    for (int ni = 0; ni < 5; ++ni) b[ni] = pb[ni][0];
    pa0 += 256; pa1 += 256;
    #pragma unroll
    for (int ni = 0; ni < 5; ++ni) pb[ni] += 1280;

    #pragma unroll 2
    for (int ck = 0; ck < NCHUNK - 1; ++ck) {
        // prefetch chunk ck+1 while computing ck
        half8 na0 = pa0[0], na1 = pa1[0];
        half8 nb[5];
        #pragma unroll
        for (int ni = 0; ni < 5; ++ni) nb[ni] = pb[ni][0];
        pa0 += 256; pa1 += 256;
        #pragma unroll
        for (int ni = 0; ni < 5; ++ni) pb[ni] += 1280;

        #pragma unroll
        for (int ni = 0; ni < 5; ++ni) {
            acc[0][ni] = __builtin_amdgcn_mfma_f32_16x16x32_f16(a0, b[ni], acc[0][ni], 0, 0, 0);
            acc[1][ni] = __builtin_amdgcn_mfma_f32_16x16x32_f16(a1, b[ni], acc[1][ni], 0, 0, 0);
        }
        a0 = na0; a1 = na1;
        #pragma unroll
        for (int ni = 0; ni < 5; ++ni) b[ni] = nb[ni];
    }
    // last chunk
    #pragma unroll
    for (int ni = 0; ni < 5; ++ni) {
        acc[0][ni] = __builtin_amdgcn_mfma_f32_16x16x32_f16(a0, b[ni], acc[0][ni], 0, 0, 0);
        acc[1][ni] = __builtin_amdgcn_mfma_f32_16x16x32_f16(a1, b[ni], acc[1][ni], 0, 0, 0);
    }

    // C layout (16x16): col = lane&15, row = (lane>>4)*4 + reg
    #pragma unroll
    for (int ni = 0; ni < 5; ++ni) {
        const int n = wn * 80 + ni * 16 + l15;
        if (n < NOUT) {
            const float bv = bfc[n];
            #pragma unroll
            for (int mi = 0; mi < 2; ++mi) {
                const int mbase = m0 + wm * 32 + mi * 16 + l4 * 4;
                #pragma unroll
                for (int g = 0; g < 4; ++g)
                    out[(size_t)(mbase + g) * NOUT + n] = acc[mi][ni][g] + bv;
            }
        }
    }
}

extern "C" void kernel_launch(void* const* d_in, const int* in_sizes, int n_in,
                              void* d_out, int out_size, void* d_ws, size_t ws_size,
                              hipStream_t stream) {
    const float* x     = (const float*)d_in[0];
    const float* Wih_f = (const float*)d_in[1];
    const float* Whh_f = (const float*)d_in[2];
    const float* bih_f = (const float*)d_in[3];
    const float* bhh_f = (const float*)d_in[4];
    const float* Wih_b = (const float*)d_in[5];
    const float* Whh_b = (const float*)d_in[6];
    const float* bih_b = (const float*)d_in[7];
    const float* bhh_b = (const float*)d_in[8];
    const float* Wfc   = (const float*)d_in[9];
    const float* bfc   = (const float*)d_in[10];
    float* out = (float*)d_out;

    // Workspace layout: [W2t: NPAD*KDIM fp16][H chunk (tiled): chunk*KDIM fp16]
    _Float16* W2 = (_Float16*)d_ws;
    size_t h_off = ((size_t)NPAD * KDIM * 2 + 255) & ~(size_t)255;
    size_t avail = (ws_size > h_off) ? (ws_size - h_off) : 0;
    long maxrows = (long)(avail / ((size_t)KDIM * 2));
    int chunk = (int)((maxrows / 128) * 128);
    if (chunk > NBATCH) chunk = NBATCH;
    if (chunk < 128)    chunk = 128;
    _Float16* Hc = (_Float16*)((char*)d_ws + h_off);

    conv_kernel<<<(NPAD * KDIM + 255) / 256, 256, 0, stream>>>(Wfc, W2);

    for (int r0 = 0; r0 < NBATCH; r0 += chunk) {
        int rows = NBATCH - r0; if (rows > chunk) rows = chunk;
        lstm_kernel<<<rows / 16, 256, 0, stream>>>(x, Wih_f, Whh_f, bih_f, bhh_f,
                                                   Wih_b, Whh_b, bih_b, bhh_b,
                                                   r0, Hc);
        gemm_kernel<<<rows / 64, 512, 0, stream>>>(Hc, W2, bfc,
                                                   out + (size_t)r0 * NOUT);
    }
}

// Round 8
// 518.914 us; speedup vs baseline: 2.7172x; 1.6087x over previous
//
#include <hip/hip_runtime.h>
#include <hip/hip_fp16.h>

#define TSTEPS 276
#define NBATCH 32768
#define KDIM   4416   // 276*16
#define NPAD   320    // Wfc rows padded to 4*80
#define NOUT   276
#define NTILE  138    // KDIM / 32 = TSTEPS / 2
#define BTILE_ELE (320 * 32)     // elements per k-tile of W2t (10240)

typedef _Float16 half8 __attribute__((ext_vector_type(8)));
typedef float    f32x4 __attribute__((ext_vector_type(4)));

__device__ __forceinline__ float fast_sigmoid(float x) {
    float e = __builtin_amdgcn_exp2f(-1.4426950408889634f * x);
    return __builtin_amdgcn_rcpf(1.0f + e);
}
__device__ __forceinline__ float fast_tanh(float x) {
    float e = __builtin_amdgcn_exp2f(2.885390081777927f * x);
    return 1.0f - 2.0f * __builtin_amdgcn_rcpf(1.0f + e);
}

// broadcast h from lane (lane&0x18)|j within each 8-lane group (BitMode swizzle)
#define HSWZ(dst, hb, j) dst = __int_as_float(__builtin_amdgcn_ds_swizzle(hb, ((j) << 5) | 0x18))

// ---------------- Kernel 1: Wfc fp32 -> fp16, K-permutation + B-TILING ------
// (unchanged, validated) W2t[k/32][320][32] fp16 = MFMA-fragment-native B.
// Storage k-index equals LSTM iteration index: p = s*16 + dir*8 + j.
__global__ __launch_bounds__(256) void conv_kernel(const float* __restrict__ Wfc,
                                                   _Float16* __restrict__ W2t)
{
    int i = blockIdx.x * 256 + threadIdx.x;        // destination index
    if (i < NPAD * KDIM) {
        int nk = i / BTILE_ELE;                    // k-tile index
        int r  = i - nk * BTILE_ELE;
        int n  = r >> 5;                           // 0..319 output row
        int kc = r & 31;
        int p  = nk * 32 + kc;                     // logical k
        _Float16 v = (_Float16)0.0f;
        if (n < NOUT) {
            int s = p >> 4, rr = p & 15;
            int src = (rr < 8) ? p : ((TSTEPS - 1 - s) * 16 + rr);
            v = (_Float16)Wfc[n * KDIM + src];
        }
        W2t[i] = v;
    }
}

// ---------------- Kernel 2: FUSED bidirectional LSTM + FC GEMM --------------
// R8: lstm (VALU-bound, idle MFMA) and gemm (latency-bound, idle VALU) are
// complementary -> fuse. Block = 64 batch rows, 1024 threads (16 waves).
// Per 2 steps: 8 lanes/(row,dir) compute h as before and write the 64x32
// H k-tile into LDS (double-buffered, XOR chunk-swizzle vs the 64B-stride
// ds_read conflict); barrier; each wave does 1 ds_read_b128 (A frag, 16 rows)
// + 5 MFMAs vs W2t fragments (wave tile 16x80, 4M x 4N wave grid), B loaded
// direct-to-VGPR at iteration top (~1100cy lstm compute covers L2 latency).
// H never touches HBM (was 280MB write + 289MB read); the separate gemm's
// latency wall (R6: MfmaUtil 6.4%, all pipes idle) disappears entirely.
// VGPR ~120 <= 128 -> 16 waves/CU (same as the standalone lstm).
__global__ __launch_bounds__(1024, 4) void fused_kernel(
    const float* __restrict__ x,
    const float* __restrict__ Wih_f, const float* __restrict__ Whh_f,
    const float* __restrict__ bih_f, const float* __restrict__ bhh_f,
    const float* __restrict__ Wih_b, const float* __restrict__ Whh_b,
    const float* __restrict__ bih_b, const float* __restrict__ bhh_b,
    const _Float16* __restrict__ W2, const float* __restrict__ bfc,
    float* __restrict__ out)
{
    __shared__ _Float16 sl[2][64][32];             // double-buffered H k-tile, 8KB

    const int tid = threadIdx.x;
    const int k   = tid & 7;                       // hidden unit 0..7
    const int dir = (tid >> 3) & 1;
    const int row = tid >> 4;                      // local batch row 0..63
    const int m0  = blockIdx.x * 64;

    const float* Wih = dir ? Wih_b : Wih_f;
    const float* Whh = dir ? Whh_b : Whh_f;
    const float* bih = dir ? bih_b : bih_f;
    const float* bhh = dir ? bhh_b : bhh_f;

    float Wk[4][8], Wi0[4], Wi1[4], bs[4];
    #pragma unroll
    for (int g = 0; g < 4; ++g) {
        int wr = g * 8 + k;                        // PyTorch gate order i,f,g,o
        #pragma unroll
        for (int j = 0; j < 8; ++j) Wk[g][j] = Whh[wr * 8 + j];
        Wi0[g] = Wih[wr * 2 + 0];
        Wi1[g] = Wih[wr * 2 + 1];
        bs[g]  = bih[wr] + bhh[wr];
    }
    #pragma unroll
    for (int g = 0; g < 4; ++g) {                  // pin weights in ArchVGPRs
        #pragma unroll
        for (int j = 0; j < 8; ++j) asm volatile("" : "+v"(Wk[g][j]));
        asm volatile("" : "+v"(Wi0[g]));
        asm volatile("" : "+v"(Wi1[g]));
        asm volatile("" : "+v"(bs[g]));
    }

    const float2* __restrict__ xrow = (const float2*)(x + (size_t)(m0 + row) * (TSTEPS * 2));

    // MFMA wave roles: 16 waves = 4(M) x 4(N); wave tile 16 rows x 80 cols
    const int lane = tid & 63;
    const int w    = tid >> 6;
    const int wm   = w >> 2;
    const int wn   = w & 3;
    const int l15  = lane & 15;
    const int l4   = lane >> 4;
    const int arow = wm * 16 + l15;                // A-frag source row in slice
    const int aoff = (l4 ^ (arow & 3)) << 3;       // swizzled element offset

    const char* pb[5];                             // B fragment base pointers
    #pragma unroll
    for (int ni = 0; ni < 5; ++ni)
        pb[ni] = (const char*)W2 + (wn * 80 + ni * 16 + l15) * 64 + l4 * 16;

    f32x4 acc[5] = {};

    // swizzled chunk element offsets for the two steps of a pair
    const int c0 = ((0 | dir) ^ (row & 3)) << 3;   // s even: chunk = dir
    const int c1 = ((2 | dir) ^ (row & 3)) << 3;   // s odd : chunk = 2|dir

    float h = 0.0f, c = 0.0f;
    float2 xq0 = xrow[dir ? (TSTEPS - 1) : 0];
    float2 xq1 = xrow[dir ? (TSTEPS - 2) : 1];

    #pragma unroll 1
    for (int t = 0; t < NTILE; ++t) {
        // B fragments for tile t (used after the barrier; ~1100cy lead)
        half8 b[5];
        #pragma unroll
        for (int ni = 0; ni < 5; ++ni)
            b[ni] = *(const half8*)(pb[ni] + (size_t)t * 20480);

        // x prefetch for pair t+1 (clamped; values unused at the tail)
        int s2 = 2 * t + 2; s2 = (s2 > TSTEPS - 1) ? (TSTEPS - 1) : s2;
        int s3 = 2 * t + 3; s3 = (s3 > TSTEPS - 1) ? (TSTEPS - 1) : s3;
        const float2 nx0 = xrow[dir ? (TSTEPS - 1 - s2) : s2];
        const float2 nx1 = xrow[dir ? (TSTEPS - 1 - s3) : s3];

        _Float16* srow = &sl[t & 1][row][0];

        // ---- LSTM step s = 2t ----
        {
            const int hb = __float_as_int(h);
            float hv[8];
            HSWZ(hv[0], hb, 0); HSWZ(hv[1], hb, 1); HSWZ(hv[2], hb, 2); HSWZ(hv[3], hb, 3);
            HSWZ(hv[4], hb, 4); HSWZ(hv[5], hb, 5); HSWZ(hv[6], hb, 6); HSWZ(hv[7], hb, 7);
            float a4[4];
            #pragma unroll
            for (int g = 0; g < 4; ++g) {
                float a = fmaf(xq0.x, Wi0[g], bs[g]);
                a = fmaf(xq0.y, Wi1[g], a);
                #pragma unroll
                for (int j = 0; j < 8; ++j) a = fmaf(Wk[g][j], hv[j], a);
                a4[g] = a;
            }
            const float ig = fast_sigmoid(a4[0]);
            const float fg = fast_sigmoid(a4[1]);
            const float gg = fast_tanh(a4[2]);
            const float og = fast_sigmoid(a4[3]);
            c = fmaf(fg, c, ig * gg);
            h = og * fast_tanh(c);
            srow[c0 + k] = (_Float16)h;
        }
        // ---- LSTM step s = 2t+1 ----
        {
            const int hb = __float_as_int(h);
            float hv[8];
            HSWZ(hv[0], hb, 0); HSWZ(hv[1], hb, 1); HSWZ(hv[2], hb, 2); HSWZ(hv[3], hb, 3);
            HSWZ(hv[4], hb, 4); HSWZ(hv[5], hb, 5); HSWZ(hv[6], hb, 6); HSWZ(hv[7], hb, 7);
            float a4[4];
            #pragma unroll
            for (int g = 0; g < 4; ++g) {
                float a = fmaf(xq1.x, Wi0[g], bs[g]);
                a = fmaf(xq1.y, Wi1[g], a);
                #pragma unroll
                for (int j = 0; j < 8; ++j) a = fmaf(Wk[g][j], hv[j], a);
                a4[g] = a;
            }
            const float ig = fast_sigmoid(a4[0]);
            const float fg = fast_sigmoid(a4[1]);
            const float gg = fast_tanh(a4[2]);
            const float og = fast_sigmoid(a4[3]);
            c = fmaf(fg, c, ig * gg);
            h = og * fast_tanh(c);
            srow[c1 + k] = (_Float16)h;
        }

        __syncthreads();                           // slice t complete (one barrier/pair:
                                                   // buf reuse at t+2 is fenced by barrier t+1)

        const half8 a = *(const half8*)(&sl[t & 1][arow][aoff]);
        #pragma unroll
        for (int ni = 0; ni < 5; ++ni)
            acc[ni] = __builtin_amdgcn_mfma_f32_16x16x32_f16(a, b[ni], acc[ni], 0, 0, 0);

        xq0 = nx0; xq1 = nx1;
    }

    // epilogue: C layout col = l15 (N), row = l4*4 + g (M within 16-row tile)
    #pragma unroll
    for (int ni = 0; ni < 5; ++ni) {
        const int n = wn * 80 + ni * 16 + l15;
        if (n < NOUT) {
            const float bv = bfc[n];
            #pragma unroll
            for (int g = 0; g < 4; ++g)
                out[(size_t)(m0 + wm * 16 + l4 * 4 + g) * NOUT + n] = acc[ni][g] + bv;
        }
    }
}

extern "C" void kernel_launch(void* const* d_in, const int* in_sizes, int n_in,
                              void* d_out, int out_size, void* d_ws, size_t ws_size,
                              hipStream_t stream) {
    const float* x     = (const float*)d_in[0];
    const float* Wih_f = (const float*)d_in[1];
    const float* Whh_f = (const float*)d_in[2];
    const float* bih_f = (const float*)d_in[3];
    const float* bhh_f = (const float*)d_in[4];
    const float* Wih_b = (const float*)d_in[5];
    const float* Whh_b = (const float*)d_in[6];
    const float* bih_b = (const float*)d_in[7];
    const float* bhh_b = (const float*)d_in[8];
    const float* Wfc   = (const float*)d_in[9];
    const float* bfc   = (const float*)d_in[10];
    float* out = (float*)d_out;

    _Float16* W2 = (_Float16*)d_ws;                // 2.76 MB, only workspace user now

    conv_kernel<<<(NPAD * KDIM + 255) / 256, 256, 0, stream>>>(Wfc, W2);
    fused_kernel<<<NBATCH / 64, 1024, 0, stream>>>(x, Wih_f, Whh_f, bih_f, bhh_f,
                                                   Wih_b, Whh_b, bih_b, bhh_b,
                                                   W2, bfc, out);
}